// Round 6
// baseline (594.520 us; speedup 1.0000x reference)
//
#include <hip/hip_runtime.h>

// KanvolutionLayer: out[b,o,hw] = (sum_{p,c} x^(p+1) Wp[p,o,c] + bp[o]) / (1 + |sum_{q,c} x^(q+1) Wq[q,o,c]|)
// MFMA GEMM, M=100352 (b*hw), K=1280 (p*256+c), N=512 (p/q outs interleaved per 16).
// R4: 128x128, 64x64/wave -> 2 blocks/CU, 401 us. R5: acc spill disaster (lesson: don't fight regalloc).
// R6: 128x64, 32x64/wave, 9x4KB LDS, 3 blocks/CU: 383 us. R7: bound(256,4) spilled + setprio hurt: 400.
// R8: f32x2 + buffer rotation: 377. R9: src-level VALU/MFMA software pipeline: 375, counters
//     IDENTICAL -> compiler already schedules; stall is structural. Ledger: wave busy only ~3.5k
//     of ~13k cyc per g; utilizations = 3 waves x duty exactly. Biggest identified wait: per-g
//     serial section (barrier -> DMA -> vmcnt(0) drain -> barrier) x2 barriers x 8 g.
// R10: stage pipelining (T3-lite).
//  - Double-buffered HI-only LDS: 2 x (4x4KB p0-3 + 2KB p4 p-cols) = 36864 B (3 blocks/CU kept).
//    Stage for g+1 issues at TOP of g's compute -> DMAs age ~3.5k cyc -> barrier drain free.
//    ONE barrier per g (9 total vs 16).
//  - lo planes DIRECT from L2 (R4's wl4 pattern generalized to p1-4): per-ni pointers, one-p-ahead
//    prefetch blC/blN. All 4 waves read identical frags -> L1 serves siblings.
//  - XN deleted: x for g+1 reloads into XV at p=3 (last XV use is p=2's update; p3+p4 MFMA covers
//    HBM latency). Same arithmetic sequence as R8/R9 -> bit-identical output.

typedef __attribute__((ext_vector_type(8))) short bf16x8;           // MFMA A/B frag (4 VGPRs)
typedef __attribute__((ext_vector_type(4))) float f32x4;            // MFMA C/D frag
typedef __attribute__((ext_vector_type(2))) float f32x2;            // packed-fp32 pair

#define CIN    256
#define HW3    3136          // 56*56
#define MTOT   100352        // 32*3136 = 784 * 128
#define KTOT   1280
#define WPLANE (512 * 1280)
#define BUFSZ  18432         // 4*4096 hi p0-3 + 2048 hi p4 (p-cols only)

__device__ __forceinline__ unsigned short f2bf(float f) {
    union { float f; unsigned int u; } cv; cv.f = f;
    unsigned int u = cv.u;
    return (unsigned short)((u + 0x7FFFu + ((u >> 16) & 1u)) >> 16);  // RNE
}
__device__ __forceinline__ float bf2f(unsigned short h) {
    union { unsigned int u; float f; } cv; cv.u = ((unsigned int)h) << 16;
    return cv.f;
}

// Pack weights into bf16 hi/lo planes [512][1280]; row n -> (o,isq):
//   o = (n>>5)*16 + (n&15), isq = (n>>4)&1  (pairs P/Q frags per 16 cols). k = p*256 + c.
__global__ void pack_w_kernel(const float* __restrict__ Wp,
                              const float* __restrict__ Wq,
                              unsigned short* __restrict__ Whi,
                              unsigned short* __restrict__ Wlo) {
    int idx = blockIdx.x * 256 + threadIdx.x;      // [0, 512*1280)
    int n = idx / KTOT;
    int k = idx - n * KTOT;
    int p = k >> 8, c = k & 255;
    int o = ((n >> 5) << 4) + (n & 15);
    int isq = (n >> 4) & 1;
    float v;
    if (isq) v = (p < 4) ? Wq[((size_t)p * 256 + o) * 256 + c] : 0.0f;
    else     v = Wp[((size_t)p * 256 + o) * 256 + c];
    unsigned short h = f2bf(v);
    Whi[idx] = h;
    Wlo[idx] = f2bf(v - bf2f(h));   // exact residual, then one rounding
}

__device__ __forceinline__ unsigned int fbits(float f) {
    union { float f; unsigned int u; } c; c.f = f; return c.u;
}
__device__ __forceinline__ float ubits(unsigned int u) {
    union { unsigned int u; float f; } c; c.u = u; return c.f;
}

// Pack top-16 bits of 4 f32x2 (8 fp32) into a bf16x8 frag (truncation) via v_perm_b32.
__device__ __forceinline__ bf16x8 pack_hi8v(const f32x2* p) {
    union { unsigned int w[4]; bf16x8 h; } r;
#pragma unroll
    for (int j = 0; j < 4; ++j)
        r.w[j] = __builtin_amdgcn_perm(fbits(p[j].y), fbits(p[j].x), 0x07060302);
    return r.h;
}
// Exact residual v - trunc16(v), vector form.
__device__ __forceinline__ void resid4v(const f32x2* v, f32x2* l) {
#pragma unroll
    for (int j = 0; j < 4; ++j) {
        f32x2 h;
        h.x = ubits(fbits(v[j].x) & 0xFFFF0000u);   // hi as fp32 (exact)
        h.y = ubits(fbits(v[j].y) & 0xFFFF0000u);
        l[j] = v[j] - h;                            // exact residual
    }
}

__global__ __launch_bounds__(256, 3) void kanv_gemm(
    const float* __restrict__ x,
    const unsigned short* __restrict__ Whi,
    const unsigned short* __restrict__ Wlo,
    const float* __restrict__ bp,
    float* __restrict__ out)
{
    __shared__ __align__(16) char sB[2 * BUFSZ];   // 36 KB double-buffered hi slabs

    const int tid  = threadIdx.x;
    const int lane = tid & 63;
    const int wave = tid >> 6;        // all 4 waves stack on m
    const int col  = lane & 15;
    const int quad = lane >> 4;

    // XCD swizzle: grid=6272=8*784; contiguous orig ranges per XCD -> 8 nt-siblings of an mt
    // share one XCD's L2 (x panel + W reuse).
    const int bid  = blockIdx.x;
    const int orig = (bid & 7) * 784 + (bid >> 3);   // bijective
    const int nt = orig & 7;                          // n-tile (8 x 64 = 512)
    const int mt = orig >> 3;                         // m-tile (784 x 128)
    const int m0 = mt * 128 + wave * 32;

    // per-mi x pointers: lane holds A[m = m0+mi*16+col][c = g*32+quad*8+j]; advance 32*HW3 per g.
    const float* xc[2];
#pragma unroll
    for (int mi = 0; mi < 2; ++mi) {
        int m  = m0 + mi * 16 + col;
        int bb = m / HW3, hw = m - bb * HW3;
        xc[mi] = x + ((size_t)bb * CIN + quad * 8) * HW3 + hw;
    }

    // lo-plane direct pointers (per ni): n = nt*64 + ni*16 + col; frag at + p*256 + g*32 elems.
    const unsigned short* wl[4];
#pragma unroll
    for (int ni = 0; ni < 4; ++ni) {
        int n = nt * 64 + ni * 16 + col;
        wl[ni] = Wlo + (size_t)n * KTOT + quad * 8;
    }

    // ---- hi staging geometry ----
    // slabs 0-3 (p=s): 1 chunk per wave: rows wave*16+col, dst s*4096 + wave*1024 + lane*16.
    // slab4 (p-cols only, rows local [0,16)u[32,48)): waves 0,2 -> dst 16384 + (wave>>1)*1024.
    const int voff  = (nt * 64 + wave * 16 + col) * 2560 + quad * 16;          // bytes
    const int voff4 = (nt * 64 + (wave >> 1) * 32 + col) * 2560 + quad * 16;   // waves 0,2

    // frag-read base within a slab chunk
    const int rbase = quad * 256 + col * 16;

    f32x4 acc[2][4];
#pragma unroll
    for (int mi = 0; mi < 2; ++mi)
#pragma unroll
        for (int ni = 0; ni < 4; ++ni)
            acc[mi][ni] = (f32x4){0.f, 0.f, 0.f, 0.f};

    // stage buffer `bs` with slabs for group g (async DMA, 4-5 instr/wave)
    auto stage = [&](int bs, int g) {
        char* dstb = sB + bs * BUFSZ;
        const char* whib = (const char*)Whi;
#pragma unroll
        for (int s = 0; s < 4; ++s) {
            __builtin_amdgcn_global_load_lds(
                (const __attribute__((address_space(1))) void*)(whib + (size_t)((s * 256 + g * 32) * 2) + voff),
                (__attribute__((address_space(3))) void*)(dstb + s * 4096 + wave * 1024),
                16, 0, 0);
        }
        if ((wave & 1) == 0) {
            __builtin_amdgcn_global_load_lds(
                (const __attribute__((address_space(1))) void*)(whib + (size_t)((4 * 256 + g * 32) * 2) + voff4),
                (__attribute__((address_space(3))) void*)(dstb + 16384 + (wave >> 1) * 1024),
                16, 0, 0);
        }
    };

    // prologue: stage g=0 into buf0 (DMA overlaps initial x load), load XV(g=0)
    stage(0, 0);
    f32x2 XV[2][4];
#pragma unroll
    for (int mi = 0; mi < 2; ++mi) {
#pragma unroll
        for (int j = 0; j < 4; ++j) {
            f32x2 v;
            v.x = xc[mi][(size_t)(2 * j) * HW3];
            v.y = xc[mi][(size_t)(2 * j + 1) * HW3];
            XV[mi][j] = v;
        }
        xc[mi] += (size_t)32 * HW3;
    }
    __syncthreads();   // drain prologue DMA (once)

    int bufo = 0;
    for (int g = 0; g < 8; ++g) {
        const char* cbuf = sB + bufo * BUFSZ;

        // issue next-g stage NOW: DMAs age through this g's compute; end-of-g barrier drain is free.
        // (writes buf^1, last read during g-1 and protected by the barrier at end of g-1)
        if (g < 7) stage(bufo ^ 1, g + 1);

        // lo(p=1) prefetch (L1/L2-resident; p0 phase covers latency)
        bf16x8 blC[4];
#pragma unroll
        for (int ni = 0; ni < 4; ++ni)
            blC[ni] = *(const bf16x8*)(wl[ni] + 1 * 256 + g * 32);

        // p0 operands: ah = trunc(x^1); pw = x^2 (same sequence as R8/R9)
        f32x2 pw[2][4];
        bf16x8 ahC[2], alC[2];
#pragma unroll
        for (int mi = 0; mi < 2; ++mi) {
            ahC[mi] = pack_hi8v(XV[mi]);
#pragma unroll
            for (int j = 0; j < 4; ++j)
                pw[mi][j] = XV[mi][j] * XV[mi][j];
        }

#pragma unroll
        for (int p = 0; p < 5; ++p) {
            // prepack operands for p+1 (independent of MFMA(p))
            bf16x8 ahN[2], alN[2], blN[4];
            if (p < 4) {
#pragma unroll
                for (int mi = 0; mi < 2; ++mi) {
                    ahN[mi] = pack_hi8v(pw[mi]);
                    f32x2 lo[4];
                    resid4v(pw[mi], lo);
                    alN[mi] = pack_hi8v(lo);
                }
                if (p < 3) {
#pragma unroll
                    for (int mi = 0; mi < 2; ++mi)
#pragma unroll
                        for (int j = 0; j < 4; ++j)
                            pw[mi][j] *= XV[mi][j];            // x^(p+3)
                }
            }
            if (p >= 1 && p < 4) {
#pragma unroll
                for (int ni = 0; ni < 4; ++ni)
                    blN[ni] = *(const bf16x8*)(wl[ni] + (p + 1) * 256 + g * 32);
            }
            if (p == 3 && g < 7) {
                // XV dead after p=2's update: reload g+1's x in place (p3+p4 MFMA covers latency)
#pragma unroll
                for (int mi = 0; mi < 2; ++mi) {
#pragma unroll
                    for (int j = 0; j < 4; ++j) {
                        f32x2 v;
                        v.x = xc[mi][(size_t)(2 * j) * HW3];
                        v.y = xc[mi][(size_t)(2 * j + 1) * HW3];
                        XV[mi][j] = v;
                    }
                    xc[mi] += (size_t)32 * HW3;
                }
            }

            // MFMA cluster for p: bh from LDS (current buffer), lo from blC regs
#pragma unroll
            for (int ni = 0; ni < 4; ++ni) {
                if (p == 4 && (ni & 1)) continue;              // q-weights zero at p=4
                const char* ba = (p < 4)
                    ? (cbuf + p * 4096 + ni * 1024 + rbase)
                    : (cbuf + 16384 + (ni >> 1) * 1024 + rbase);
                bf16x8 bh = *(const bf16x8*)ba;
#pragma unroll
                for (int mi = 0; mi < 2; ++mi)
                    acc[mi][ni] = __builtin_amdgcn_mfma_f32_16x16x32_bf16(ahC[mi], bh, acc[mi][ni], 0, 0, 0);
                if (p > 0) {
#pragma unroll
                    for (int mi = 0; mi < 2; ++mi) {
                        acc[mi][ni] = __builtin_amdgcn_mfma_f32_16x16x32_bf16(alC[mi], bh, acc[mi][ni], 0, 0, 0);
                        acc[mi][ni] = __builtin_amdgcn_mfma_f32_16x16x32_bf16(ahC[mi], blC[ni], acc[mi][ni], 0, 0, 0);
                    }
                }
            }

            // rotate
            if (p < 4) {
#pragma unroll
                for (int mi = 0; mi < 2; ++mi) { ahC[mi] = ahN[mi]; alC[mi] = alN[mi]; }
                if (p >= 1) {
#pragma unroll
                    for (int ni = 0; ni < 4; ++ni) blC[ni] = blN[ni];
                }
            }
        }

        __syncthreads();   // all waves done reading cbuf; next-g DMAs (aged) drained for free
        bufo ^= 1;
    }

    // ---- epilogue (verified R2/R3): pair (sum_p, sum_q) frags, bias, divide, float4 store ----
#pragma unroll
    for (int j = 0; j < 2; ++j) {
        const int o = (nt * 2 + j) * 16 + col;
        const float bias = bp[o];
#pragma unroll
        for (int mi = 0; mi < 2; ++mi) {
            f32x4 sp = acc[mi][2 * j];
            f32x4 sq = acc[mi][2 * j + 1];
            const int mrow = m0 + mi * 16 + quad * 4;  // 4 consecutive hw, same image
            const int b2  = mrow / HW3;
            const int hw2 = mrow - b2 * HW3;
            float4 v;
            v.x = (sp[0] + bias) / (1.0f + fabsf(sq[0]));
            v.y = (sp[1] + bias) / (1.0f + fabsf(sq[1]));
            v.z = (sp[2] + bias) / (1.0f + fabsf(sq[2]));
            v.w = (sp[3] + bias) / (1.0f + fabsf(sq[3]));
            *(float4*)&out[((size_t)b2 * 256 + o) * HW3 + hw2] = v;
        }
    }
}

extern "C" void kernel_launch(void* const* d_in, const int* in_sizes, int n_in,
                              void* d_out, int out_size, void* d_ws, size_t ws_size,
                              hipStream_t stream) {
    const float* x  = (const float*)d_in[0];
    const float* Wp = (const float*)d_in[1];
    const float* bp = (const float*)d_in[2];
    const float* Wq = (const float*)d_in[3];
    float* out = (float*)d_out;
    unsigned short* Whi = (unsigned short*)d_ws;              // 1.31 MB
    unsigned short* Wlo = Whi + WPLANE;                        // +1.31 MB

    pack_w_kernel<<<WPLANE / 256, 256, 0, stream>>>(Wp, Wq, Whi, Wlo);
    kanv_gemm<<<(MTOT / 128) * 8, 256, 0, stream>>>(x, Whi, Wlo, bp, out);
}